// Round 1
// baseline (429.618 us; speedup 1.0000x reference)
//
#include <hip/hip_runtime.h>
#include <hip/hip_bf16.h>
#include <stdint.h>

// ---------------------------------------------------------------------------
// Decoder (teacher-forced, state never advances):
//   gates = x @ W_ih^T + (h0 @ W_hh^T + b_ih + b_hh)  (broadcast over t)
//   i,f,g,o = split(gates); c' = sig(f)*c0 + sig(i)*tanh(g); h' = sig(o)*tanh(c')
//   out = h' @ fc_w^T + fc_b
// Sizes: B=64, T=1024, D=513, H=512, 4H=2048.  M = B*T = 65536.
// Strategy: bf16 MFMA (16x16x32) for both GEMMs, fp32 accum.
// ---------------------------------------------------------------------------

typedef __bf16 bf16x8 __attribute__((ext_vector_type(8)));
typedef float f32x4 __attribute__((ext_vector_type(4)));

#define MFMA_BF16 __builtin_amdgcn_mfma_f32_16x16x32_bf16

// async global->LDS, 16B per lane. LDS dest is wave-uniform base + lane*16.
__device__ __forceinline__ void gld16(const void* gptr, void* lptr) {
  __builtin_amdgcn_global_load_lds(
      (const __attribute__((address_space(1))) void*)gptr,
      (__attribute__((address_space(3))) void*)lptr, 16, 0, 0);
}

// --------------------------- pack fp32 -> bf16 ------------------------------
// out[r][c] = (r < rows_in && c < kin) ? bf16(in[r][c]) : 0   ; grid.x = rows_out
__global__ void pack_bf16_kernel(const float* __restrict__ in,
                                 __bf16* __restrict__ out,
                                 int rows_in, int kin, int kout) {
  const int r = blockIdx.x;
  for (int c = threadIdx.x; c < kout; c += 256) {
    float v = (r < rows_in && c < kin) ? in[(size_t)r * kin + c] : 0.f;
    out[(size_t)r * kout + c] = (__bf16)v;
  }
}

// --------------------------- hbias ------------------------------------------
// hbias[b][g] = dot(h0[b,:], W_hh[g,:]) + b_ih[g] + b_hh[g]   (fp32 exact-ish)
// one wave per (b,g); block = 4 waves; grid = 64*2048/4 = 32768
__global__ void hbias_kernel(const float* __restrict__ h0,
                             const float* __restrict__ Whh,
                             const float* __restrict__ bih,
                             const float* __restrict__ bhh,
                             float* __restrict__ hbias) {
  const int t = threadIdx.x, w = t >> 6, l = t & 63;
  const int b = blockIdx.x >> 9;
  const int g = ((blockIdx.x & 511) << 2) | w;
  const float* hr = h0 + b * 512;
  const float* wr = Whh + (size_t)g * 512;
  float s = 0.f;
#pragma unroll
  for (int h = 0; h < 512; h += 64) s = fmaf(hr[h + l], wr[h + l], s);
#pragma unroll
  for (int off = 32; off; off >>= 1) s += __shfl_down(s, off);
  if (l == 0) hbias[b * 2048 + g] = s + bih[g] + bhh[g];
}

// --------------------------- GEMM1 + LSTM cell ------------------------------
// gates[m][j*512+h] = sum_k xbf[m][k] * wbf[j*512+h][k]   (K padded to 544)
// block: 256 thr = 4 waves, tile BM=128 x (BNH=32 h-cols x 4 gates), BK=32.
// wave w owns rows [w*32, w*32+32). epilogue: LSTM cell -> hnew bf16 [M][512]
__global__ __launch_bounds__(256) void gemm1_kernel(
    const __bf16* __restrict__ xbf, const __bf16* __restrict__ wbf,
    const float* __restrict__ hbias, const float* __restrict__ c0,
    __bf16* __restrict__ hnew) {
  const int t = threadIdx.x;
  const int w = t >> 6, l = t & 63;
  const int ntile = blockIdx.x & 15;   // fastest: 16 blocks share the A panel
  const int mtile = blockIdx.x >> 4;
  const int m0 = mtile << 7;
  const int n0 = ntile << 5;

  __shared__ __align__(16) __bf16 As[128 * 32];      // [row][k] 64B rows
  __shared__ __align__(16) __bf16 Bs[4 * 32 * 32];   // [gate][col][k]

  f32x4 acc[4][2][2];
#pragma unroll
  for (int j = 0; j < 4; ++j)
#pragma unroll
    for (int mi = 0; mi < 2; ++mi)
#pragma unroll
      for (int ni = 0; ni < 2; ++ni) acc[j][mi][ni] = (f32x4){0.f, 0.f, 0.f, 0.f};

  // staging source addresses (per lane); dest LDS byte = t*16 (linear)
  const int arow = t >> 2;            // 0..63
  const int akp = (t & 3) << 3;       // k-element offset 0,8,16,24
  const __bf16* ag = xbf + (size_t)(m0 + arow) * 544 + akp;
  const int bj = t >> 7;              // gate 0/1 (q adds 2)
  const int bcol = (t & 127) >> 2;    // 0..31
  const __bf16* bg = wbf + (size_t)(bj * 512 + n0 + bcol) * 544 + akp;

  char* asb = (char*)As;
  char* bsb = (char*)Bs;
  const int wofs = w << 10;           // wave-uniform LDS base
  const int lrow = l & 15;
  const int lk = (l >> 4) << 4;       // byte offset of k-fragment within row

  for (int kt = 0; kt < 17; ++kt) {
    const int kof = kt << 5;
    gld16(ag + kof, asb + wofs);
    gld16(ag + kof + 64 * 544, asb + 4096 + wofs);
    gld16(bg + kof, bsb + wofs);
    gld16(bg + kof + 1024 * 544, bsb + 4096 + wofs);
    __syncthreads();  // drains vmcnt before any wave reads LDS

    bf16x8 a0 = *(const bf16x8*)(asb + ((w * 32 + lrow) << 6) + lk);
    bf16x8 a1 = *(const bf16x8*)(asb + ((w * 32 + 16 + lrow) << 6) + lk);
#pragma unroll
    for (int j = 0; j < 4; ++j) {
      bf16x8 b0 = *(const bf16x8*)(bsb + (j << 11) + (lrow << 6) + lk);
      bf16x8 b1 = *(const bf16x8*)(bsb + (j << 11) + ((16 + lrow) << 6) + lk);
      acc[j][0][0] = MFMA_BF16(a0, b0, acc[j][0][0], 0, 0, 0);
      acc[j][0][1] = MFMA_BF16(a0, b1, acc[j][0][1], 0, 0, 0);
      acc[j][1][0] = MFMA_BF16(a1, b0, acc[j][1][0], 0, 0, 0);
      acc[j][1][1] = MFMA_BF16(a1, b1, acc[j][1][1], 0, 0, 0);
    }
    __syncthreads();
  }

  // epilogue: LSTM cell. C/D layout: col = lane&15, row = (lane>>4)*4 + reg.
  const int lr4 = (l >> 4) << 2;
#pragma unroll
  for (int mi = 0; mi < 2; ++mi) {
#pragma unroll
    for (int ni = 0; ni < 2; ++ni) {
#pragma unroll
      for (int r = 0; r < 4; ++r) {
        const int m = m0 + w * 32 + mi * 16 + lr4 + r;
        const int h = n0 + ni * 16 + lrow;
        const int b = m >> 10;
        const float* hb = hbias + b * 2048 + h;
        const float gi = acc[0][mi][ni][r] + hb[0];
        const float gf = acc[1][mi][ni][r] + hb[512];
        const float gg = acc[2][mi][ni][r] + hb[1024];
        const float go = acc[3][mi][ni][r] + hb[1536];
        const float si = 1.f / (1.f + __expf(-gi));
        const float sf = 1.f / (1.f + __expf(-gf));
        const float tg = tanhf(gg);
        const float so = 1.f / (1.f + __expf(-go));
        const float cn = sf * c0[b * 512 + h] + si * tg;
        const float hv = so * tanhf(cn);
        hnew[(size_t)m * 512 + h] = (__bf16)hv;
      }
    }
  }
}

// --------------------------- GEMM2 + bias -----------------------------------
// out[m][n] = sum_h hnew[m][h]*fcw[n][h] + fcb[n] ; fcw padded to 640 rows of 0
// block: 256 thr / 4 waves, BM=128, BN=128, BK=32, K=512. grid (5, 512).
__global__ __launch_bounds__(256) void gemm2_kernel(
    const __bf16* __restrict__ hnew, const __bf16* __restrict__ fcw,
    const float* __restrict__ fcb, float* __restrict__ out) {
  const int t = threadIdx.x;
  const int w = t >> 6, l = t & 63;
  const int n0 = blockIdx.x << 7;
  const int m0 = blockIdx.y << 7;

  __shared__ __align__(16) __bf16 As[128 * 32];
  __shared__ __align__(16) __bf16 Bs[128 * 32];

  f32x4 acc[2][8];
#pragma unroll
  for (int mi = 0; mi < 2; ++mi)
#pragma unroll
    for (int ni = 0; ni < 8; ++ni) acc[mi][ni] = (f32x4){0.f, 0.f, 0.f, 0.f};

  const int arow = t >> 2;
  const int akp = (t & 3) << 3;
  const __bf16* ag = hnew + (size_t)(m0 + arow) * 512 + akp;
  const __bf16* bg = fcw + (size_t)(n0 + arow) * 512 + akp;

  char* asb = (char*)As;
  char* bsb = (char*)Bs;
  const int wofs = w << 10;
  const int lrow = l & 15;
  const int lk = (l >> 4) << 4;

  for (int kt = 0; kt < 16; ++kt) {
    const int kof = kt << 5;
    gld16(ag + kof, asb + wofs);
    gld16(ag + kof + 64 * 512, asb + 4096 + wofs);
    gld16(bg + kof, bsb + wofs);
    gld16(bg + kof + 64 * 512, bsb + 4096 + wofs);
    __syncthreads();

    bf16x8 a0 = *(const bf16x8*)(asb + ((w * 32 + lrow) << 6) + lk);
    bf16x8 a1 = *(const bf16x8*)(asb + ((w * 32 + 16 + lrow) << 6) + lk);
#pragma unroll
    for (int ni = 0; ni < 8; ++ni) {
      bf16x8 b = *(const bf16x8*)(bsb + ((ni * 16 + lrow) << 6) + lk);
      acc[0][ni] = MFMA_BF16(a0, b, acc[0][ni], 0, 0, 0);
      acc[1][ni] = MFMA_BF16(a1, b, acc[1][ni], 0, 0, 0);
    }
    __syncthreads();
  }

  const int lr4 = (l >> 4) << 2;
#pragma unroll
  for (int mi = 0; mi < 2; ++mi) {
#pragma unroll
    for (int ni = 0; ni < 8; ++ni) {
      const int n = n0 + ni * 16 + lrow;
      if (n < 513) {
        const float bias = fcb[n];
#pragma unroll
        for (int r = 0; r < 4; ++r) {
          const int m = m0 + w * 32 + mi * 16 + lr4 + r;
          out[(size_t)m * 513 + n] = acc[mi][ni][r] + bias;
        }
      }
    }
  }
}

// --------------------------- launch -----------------------------------------
extern "C" void kernel_launch(void* const* d_in, const int* in_sizes, int n_in,
                              void* d_out, int out_size, void* d_ws, size_t ws_size,
                              hipStream_t stream) {
  const float* x = (const float*)d_in[0];     // [64,1024,513]
  const float* h0 = (const float*)d_in[1];    // [1,64,512]
  const float* c0 = (const float*)d_in[2];    // [1,64,512]
  const float* Wih = (const float*)d_in[3];   // [2048,513]
  const float* Whh = (const float*)d_in[4];   // [2048,512]
  const float* bih = (const float*)d_in[5];   // [2048]
  const float* bhh = (const float*)d_in[6];   // [2048]
  const float* fcw = (const float*)d_in[7];   // [513,512]
  const float* fcb = (const float*)d_in[8];   // [513]
  float* out = (float*)d_out;                 // [64,1024,513]

  char* ws = (char*)d_ws;
  __bf16* xbf = (__bf16*)(ws);                       // 65536*544*2 = 71,303,168
  __bf16* wbf = (__bf16*)(ws + 71303168);            //  2048*544*2 =  2,228,224
  __bf16* fwbf = (__bf16*)(ws + 73531392);           //   640*512*2 =    655,360
  float* hb = (float*)(ws + 74186752);               //   64*2048*4 =    524,288
  __bf16* hn = (__bf16*)(ws + 74711040);             // 65536*512*2 = 67,108,864
  // total ws use: 141,819,904 bytes

  pack_bf16_kernel<<<65536, 256, 0, stream>>>(x, xbf, 65536, 513, 544);
  pack_bf16_kernel<<<2048, 256, 0, stream>>>(Wih, wbf, 2048, 513, 544);
  pack_bf16_kernel<<<640, 256, 0, stream>>>(fcw, fwbf, 513, 512, 512);
  hbias_kernel<<<32768, 256, 0, stream>>>(h0, Whh, bih, bhh, hb);
  gemm1_kernel<<<8192, 256, 0, stream>>>(xbf, wbf, hb, c0, hn);
  gemm2_kernel<<<dim3(5, 512), 256, 0, stream>>>(hn, fwbf, fcb, out);
}

// Round 2
// 402.823 us; speedup vs baseline: 1.0665x; 1.0665x over previous
//
#include <hip/hip_runtime.h>
#include <hip/hip_bf16.h>
#include <stdint.h>

// ---------------------------------------------------------------------------
// Decoder (teacher-forced, state never advances):
//   gates = x @ W_ih^T + (h0 @ W_hh^T + b_ih + b_hh)  (broadcast over t)
//   i,f,g,o = split(gates); c' = sig(f)*c0 + sig(i)*tanh(g); h' = sig(o)*tanh(c')
//   out = h' @ fc_w^T + fc_b
// Sizes: B=64, T=1024, D=513, H=512, 4H=2048.  M = B*T = 65536.
// R1: 2-phase double-buffered LDS (T3-min), chunk-XOR swizzle on src+read
//     (rule #21), m97 wave split (4 A + 4 B ds_reads, 16 MFMA / kstep / wave),
//     fast tanh/sigmoid epilogue, XCD-aware block swizzle.
// ---------------------------------------------------------------------------

typedef __bf16 bf16x8 __attribute__((ext_vector_type(8)));
typedef float f32x4 __attribute__((ext_vector_type(4)));

#define MFMA_BF16 __builtin_amdgcn_mfma_f32_16x16x32_bf16

// async global->LDS, 16B per lane. LDS dest must be wave-uniform; HW adds lane*16.
__device__ __forceinline__ void gld16(const void* gptr, void* lptr) {
  __builtin_amdgcn_global_load_lds(
      (const __attribute__((address_space(1))) void*)gptr,
      (__attribute__((address_space(3))) void*)lptr, 16, 0, 0);
}

__device__ __forceinline__ float fsigm(float x) {
  x = fminf(fmaxf(x, -30.f), 30.f);
  return __frcp_rn(1.f + __expf(-x));
}
__device__ __forceinline__ float ftanh(float x) {
  x = fminf(fmaxf(x, -15.f), 15.f);
  const float e = __expf(2.f * x);
  return (e - 1.f) * __frcp_rn(e + 1.f);
}

// --------------------------- pack fp32 -> bf16 ------------------------------
// out[r][c] = (r < rows_in && c < kin) ? bf16(in[r][c]) : 0 ; grid.x = rows_out
// paired 4B stores; kout must be even.
__global__ void pack_bf16_kernel(const float* __restrict__ in,
                                 __bf16* __restrict__ out,
                                 int rows_in, int kin, int kout) {
  const int r = blockIdx.x;
  const bool rv = r < rows_in;
  for (int c = threadIdx.x * 2; c < kout; c += 512) {
    float v0 = (rv && c < kin) ? in[(size_t)r * kin + c] : 0.f;
    float v1 = (rv && c + 1 < kin) ? in[(size_t)r * kin + c + 1] : 0.f;
    union { __bf16 h[2]; uint32_t u; } p;
    p.h[0] = (__bf16)v0;
    p.h[1] = (__bf16)v1;
    *(uint32_t*)&out[(size_t)r * kout + c] = p.u;
  }
}

// --------------------------- hbias ------------------------------------------
// hbias[b][g] = dot(h0[b,:], W_hh[g,:]) + b_ih[g] + b_hh[g]
__global__ void hbias_kernel(const float* __restrict__ h0,
                             const float* __restrict__ Whh,
                             const float* __restrict__ bih,
                             const float* __restrict__ bhh,
                             float* __restrict__ hbias) {
  const int t = threadIdx.x, w = t >> 6, l = t & 63;
  const int b = blockIdx.x >> 9;
  const int g = ((blockIdx.x & 511) << 2) | w;
  const float* hr = h0 + b * 512;
  const float* wr = Whh + (size_t)g * 512;
  float s = 0.f;
#pragma unroll
  for (int h = 0; h < 512; h += 64) s = fmaf(hr[h + l], wr[h + l], s);
#pragma unroll
  for (int off = 32; off; off >>= 1) s += __shfl_down(s, off);
  if (l == 0) hbias[b * 2048 + g] = s + bih[g] + bhh[g];
}

// --------------------------- GEMM1 + LSTM cell ------------------------------
// gates[m][j*512+h] = sum_k xbf[m][k] * wbf[j*512+h][k]   (K padded to 544)
// 256 thr = 4 waves (2x2). BM=128 rows; B-tile = 32 h-cols x 4 gates = 128 c.
// wave (wr,wc): rows wr*64..+64, gates all 4, h-cols n0+wc*16..+16.
// LDS chunk swizzle: LDS chunk c of row r holds global chunk c ^ ((r>>2)&3).
__global__ __launch_bounds__(256) void gemm1_kernel(
    const __bf16* __restrict__ xbf, const __bf16* __restrict__ wbf,
    const float* __restrict__ hbias, const float* __restrict__ c0,
    __bf16* __restrict__ hnew) {
  const int t = threadIdx.x;
  const int w = t >> 6, l = t & 63;
  const int wr = w >> 1, wc = w & 1;
  const int lrow = l & 15, lkq = l >> 4;

  // XCD swizzle: 8192 blocks % 8 == 0; 16 consecutive swz share one A panel.
  const int bid = blockIdx.x;
  const int swz = (bid & 7) * 1024 + (bid >> 3);
  const size_t m0 = (size_t)(swz >> 4) << 7;
  const int n0 = (swz & 15) << 5;

  __shared__ __align__(16) __bf16 As[2][128 * 32];
  __shared__ __align__(16) __bf16 Bs[2][128 * 32];

  f32x4 acc[4][4];
#pragma unroll
  for (int mi = 0; mi < 4; ++mi)
#pragma unroll
    for (int j = 0; j < 4; ++j) acc[mi][j] = (f32x4){0.f, 0.f, 0.f, 0.f};

  // staging: thread t fills LDS row sr=t>>2, chunk t&3 (linear dest);
  // source chunk pre-XORed so LDS chunk c holds global chunk c^f(sr).
  const int sr = t >> 2;
  const int sch = (t & 3) ^ ((t >> 4) & 3);          // (t&3) ^ f(sr)
  const __bf16* ag = xbf + (m0 + sr) * 544 + sch * 8;
  const int bj = sr >> 5;                            // gate 0/1 (second gld +2)
  const int bc = sr & 31;
  const __bf16* bg = wbf + (size_t)(bj * 512 + n0 + bc) * 544 + sch * 8;
  const int wofs = w << 10;                          // wave-uniform LDS base

  // reads: chunk = lkq ^ f(row); f(row) == (lrow>>2)&3 for all our frags.
  const int ch = lkq ^ ((lrow >> 2) & 3);
  const int abase = (wr * 64 + lrow) * 64 + ch * 16; // + mi*1024
  const int bbase = (wc * 16 + lrow) * 64 + ch * 16; // + j*2048

  // prologue
  {
    char* ab = (char*)As[0];
    char* bb = (char*)Bs[0];
    gld16(ag, ab + wofs);
    gld16(ag + 64 * 544, ab + 4096 + wofs);
    gld16(bg, bb + wofs);
    gld16(bg + 1024 * 544, bb + 4096 + wofs);
  }
  __syncthreads();

  for (int kt = 0; kt < 17; ++kt) {
    const int bi = kt & 1;
    if (kt < 16) {  // stage next tile into the other buffer (overlaps compute)
      const int kof = (kt + 1) << 5;
      char* ab = (char*)As[bi ^ 1];
      char* bb = (char*)Bs[bi ^ 1];
      gld16(ag + kof, ab + wofs);
      gld16(ag + kof + 64 * 544, ab + 4096 + wofs);
      gld16(bg + kof, bb + wofs);
      gld16(bg + kof + 1024 * 544, bb + 4096 + wofs);
    }
    const char* ab = (const char*)As[bi];
    const char* bb = (const char*)Bs[bi];
    bf16x8 af[4], bfr[4];
#pragma unroll
    for (int mi = 0; mi < 4; ++mi) af[mi] = *(const bf16x8*)(ab + abase + mi * 1024);
#pragma unroll
    for (int j = 0; j < 4; ++j) bfr[j] = *(const bf16x8*)(bb + bbase + j * 2048);
#pragma unroll
    for (int mi = 0; mi < 4; ++mi)
#pragma unroll
      for (int j = 0; j < 4; ++j)
        acc[mi][j] = MFMA_BF16(af[mi], bfr[j], acc[mi][j], 0, 0, 0);
    __syncthreads();  // drains vmcnt(0): next tile landed; LDS reads done
  }

  // epilogue: LSTM cell. C/D: col = lane&15 (h), row = lkq*4 + r (m offset).
  const int h = n0 + wc * 16 + lrow;
  const int b = (int)(m0 >> 10);                     // block fully inside one b
  const float hb0 = hbias[b * 2048 + h];
  const float hb1 = hbias[b * 2048 + 512 + h];
  const float hb2 = hbias[b * 2048 + 1024 + h];
  const float hb3 = hbias[b * 2048 + 1536 + h];
  const float c0v = c0[b * 512 + h];
#pragma unroll
  for (int mi = 0; mi < 4; ++mi) {
#pragma unroll
    for (int r = 0; r < 4; ++r) {
      const size_t m = m0 + wr * 64 + mi * 16 + lkq * 4 + r;
      const float gi = acc[mi][0][r] + hb0;
      const float gf = acc[mi][1][r] + hb1;
      const float gg = acc[mi][2][r] + hb2;
      const float go = acc[mi][3][r] + hb3;
      const float cn = fsigm(gf) * c0v + fsigm(gi) * ftanh(gg);
      hnew[m * 512 + h] = (__bf16)(fsigm(go) * ftanh(cn));
    }
  }
}

// --------------------------- GEMM2 + bias -----------------------------------
// out[m][n] = sum_h hnew[m][h]*fcw[n][h] + fcb[n] ; fcw padded to 640 rows.
// Same structure: BM=128, BN=128, BK=32, K=512 -> 16 ksteps. grid 2560.
__global__ __launch_bounds__(256) void gemm2_kernel(
    const __bf16* __restrict__ hnew, const __bf16* __restrict__ fcw,
    const float* __restrict__ fcb, float* __restrict__ out) {
  const int t = threadIdx.x;
  const int w = t >> 6, l = t & 63;
  const int wr = w >> 1, wc = w & 1;
  const int lrow = l & 15, lkq = l >> 4;

  const int bid = blockIdx.x;                        // 2560 % 8 == 0
  const int swz = (bid & 7) * 320 + (bid >> 3);
  const int ntile = swz % 5;
  const size_t m0 = (size_t)(swz / 5) << 7;
  const int n0 = ntile << 7;

  __shared__ __align__(16) __bf16 As[2][128 * 32];
  __shared__ __align__(16) __bf16 Bs[2][128 * 32];

  f32x4 acc[4][4];
#pragma unroll
  for (int mi = 0; mi < 4; ++mi)
#pragma unroll
    for (int ni = 0; ni < 4; ++ni) acc[mi][ni] = (f32x4){0.f, 0.f, 0.f, 0.f};

  const int sr = t >> 2;
  const int sch = (t & 3) ^ ((t >> 4) & 3);
  const __bf16* ag = hnew + (m0 + sr) * 512 + sch * 8;
  const __bf16* bg = fcw + (size_t)(n0 + sr) * 512 + sch * 8;
  const int wofs = w << 10;

  const int ch = lkq ^ ((lrow >> 2) & 3);
  const int abase = (wr * 64 + lrow) * 64 + ch * 16;  // + mi*1024
  const int bbase = (wc * 64 + lrow) * 64 + ch * 16;  // + ni*1024

  {
    char* ab = (char*)As[0];
    char* bb = (char*)Bs[0];
    gld16(ag, ab + wofs);
    gld16(ag + 64 * 512, ab + 4096 + wofs);
    gld16(bg, bb + wofs);
    gld16(bg + 64 * 512, bb + 4096 + wofs);
  }
  __syncthreads();

  for (int kt = 0; kt < 16; ++kt) {
    const int bi = kt & 1;
    if (kt < 15) {
      const int kof = (kt + 1) << 5;
      char* ab = (char*)As[bi ^ 1];
      char* bb = (char*)Bs[bi ^ 1];
      gld16(ag + kof, ab + wofs);
      gld16(ag + kof + 64 * 512, ab + 4096 + wofs);
      gld16(bg + kof, bb + wofs);
      gld16(bg + kof + 64 * 512, bb + 4096 + wofs);
    }
    const char* ab = (const char*)As[bi];
    const char* bb = (const char*)Bs[bi];
    bf16x8 af[4], bfr[4];
#pragma unroll
    for (int mi = 0; mi < 4; ++mi) af[mi] = *(const bf16x8*)(ab + abase + mi * 1024);
#pragma unroll
    for (int ni = 0; ni < 4; ++ni) bfr[ni] = *(const bf16x8*)(bb + bbase + ni * 1024);
#pragma unroll
    for (int mi = 0; mi < 4; ++mi)
#pragma unroll
      for (int ni = 0; ni < 4; ++ni)
        acc[mi][ni] = MFMA_BF16(af[mi], bfr[ni], acc[mi][ni], 0, 0, 0);
    __syncthreads();
  }

#pragma unroll
  for (int ni = 0; ni < 4; ++ni) {
    const int n = n0 + wc * 64 + ni * 16 + lrow;
    if (n < 513) {
      const float bias = fcb[n];
#pragma unroll
      for (int mi = 0; mi < 4; ++mi) {
#pragma unroll
        for (int r = 0; r < 4; ++r) {
          const size_t m = m0 + wr * 64 + mi * 16 + lkq * 4 + r;
          out[m * 513 + n] = acc[mi][ni][r] + bias;
        }
      }
    }
  }
}

// --------------------------- launch -----------------------------------------
extern "C" void kernel_launch(void* const* d_in, const int* in_sizes, int n_in,
                              void* d_out, int out_size, void* d_ws, size_t ws_size,
                              hipStream_t stream) {
  const float* x = (const float*)d_in[0];     // [64,1024,513]
  const float* h0 = (const float*)d_in[1];    // [1,64,512]
  const float* c0 = (const float*)d_in[2];    // [1,64,512]
  const float* Wih = (const float*)d_in[3];   // [2048,513]
  const float* Whh = (const float*)d_in[4];   // [2048,512]
  const float* bih = (const float*)d_in[5];   // [2048]
  const float* bhh = (const float*)d_in[6];   // [2048]
  const float* fcw = (const float*)d_in[7];   // [513,512]
  const float* fcb = (const float*)d_in[8];   // [513]
  float* out = (float*)d_out;                 // [64,1024,513]

  char* ws = (char*)d_ws;
  __bf16* xbf = (__bf16*)(ws);                       // 65536*544*2 = 71,303,168
  __bf16* wbf = (__bf16*)(ws + 71303168);            //  2048*544*2 =  2,228,224
  __bf16* fwbf = (__bf16*)(ws + 73531392);           //   640*512*2 =    655,360
  float* hb = (float*)(ws + 74186752);               //   64*2048*4 =    524,288
  __bf16* hn = (__bf16*)(ws + 74711040);             // 65536*512*2 = 67,108,864

  pack_bf16_kernel<<<65536, 256, 0, stream>>>(x, xbf, 65536, 513, 544);
  pack_bf16_kernel<<<2048, 256, 0, stream>>>(Wih, wbf, 2048, 513, 544);
  pack_bf16_kernel<<<640, 256, 0, stream>>>(fcw, fwbf, 513, 512, 512);
  hbias_kernel<<<32768, 256, 0, stream>>>(h0, Whh, bih, bhh, hb);
  gemm1_kernel<<<8192, 256, 0, stream>>>(xbf, wbf, hb, c0, hn);
  gemm2_kernel<<<dim3(2560), 256, 0, stream>>>(hn, fwbf, fcb, out);
}